// Round 10
// baseline (269.660 us; speedup 1.0000x reference)
//
#include <hip/hip_runtime.h>

// Problem constants (from reference)
constexpr int B = 256, L = 500, D = 3, C = 32, I = 35, H = 512, O = 15, M = 5;
constexpr int JP = 48;   // Vt row stride (rows 0..34 live)
constexpr int KPV = 520; // padded K leading dim for Vt
constexpr int G = 100;   // scan chunks
constexpr int LC = 5;    // L / G

typedef __attribute__((ext_vector_type(8))) _Float16 half8;  // MFMA A/B frag
typedef __attribute__((ext_vector_type(2))) _Float16 half2;
typedef __attribute__((ext_vector_type(16))) float f32x16;   // 32x32 C/D frag

__device__ __forceinline__ half8 pk8(float a0, float a1, float a2, float a3,
                                     float a4, float a5, float a6, float a7) {
  half2 p0 = __builtin_bit_cast(half2, __builtin_amdgcn_cvt_pkrtz(a0, a1));
  half2 p1 = __builtin_bit_cast(half2, __builtin_amdgcn_cvt_pkrtz(a2, a3));
  half2 p2 = __builtin_bit_cast(half2, __builtin_amdgcn_cvt_pkrtz(a4, a5));
  half2 p3 = __builtin_bit_cast(half2, __builtin_amdgcn_cvt_pkrtz(a6, a7));
  return (half8){p0.x, p0.y, p1.x, p1.y, p2.x, p2.y, p3.x, p3.y};
}

// K-order for GEMM1 (permutation-invariant dot): k=0..31 -> z col k,
// k=32..34 -> inp col k-32, k>=35 pad. x-frags = float4 from raw z;
// W-frags = scalar W[i*H+h], lane=h -> 128B-coalesced across lanes.
// xf[kt] elem e: k = 16*kt + 8*hi32 + e.
__device__ __forceinline__ void load_x(const float* __restrict__ inp,
                                       const float* __restrict__ z,
                                       int l, int b, int hi32, half8 xf[3]) {
  const float* zr = z + ((size_t)b * L + l) * C + 8 * hi32;
  float4 z0 = *(const float4*)zr, z1 = *(const float4*)(zr + 4);
  float4 z2 = *(const float4*)(zr + 16), z3 = *(const float4*)(zr + 20);
  xf[0] = pk8(z0.x, z0.y, z0.z, z0.w, z1.x, z1.y, z1.z, z1.w);
  xf[1] = pk8(z2.x, z2.y, z2.z, z2.w, z3.x, z3.y, z3.z, z3.w);
  const float* ip = inp + ((size_t)b * L + l) * D;
  float i0 = ip[0], i1 = ip[1], i2 = ip[2];
  if (hi32) { i0 = 0.f; i1 = 0.f; i2 = 0.f; }
  xf[2] = pk8(i0, i1, i2, 0.f, 0.f, 0.f, 0.f, 0.f);
}

// wf[mt*3+kt] elem e: i = perm(16kt+8hi32+e): kt0 -> 3+8hi32+e,
// kt1 -> 19+8hi32+e, kt2 -> e (hi32=0, e<3) else 0.
__device__ __forceinline__ void load_w(const float* __restrict__ W,
                                       int l, int hbase, int ln31, int hi32,
                                       half8 wf[12]) {
  const float* Wc = W + (size_t)l * I * H + hbase + ln31;
#pragma unroll
  for (int mt = 0; mt < 4; ++mt) {
    const float* Wm = Wc + 32 * mt;
    float a[8], bq[8];
#pragma unroll
    for (int e = 0; e < 8; ++e) a[e] = Wm[(size_t)(3 + 8 * hi32 + e) * H];
#pragma unroll
    for (int e = 0; e < 8; ++e) bq[e] = Wm[(size_t)(19 + 8 * hi32 + e) * H];
    wf[mt * 3 + 0] = pk8(a[0], a[1], a[2], a[3], a[4], a[5], a[6], a[7]);
    wf[mt * 3 + 1] = pk8(bq[0], bq[1], bq[2], bq[3], bq[4], bq[5], bq[6], bq[7]);
    float c0 = Wm[0], c1 = Wm[(size_t)H], c2 = Wm[(size_t)2 * H];
    if (hi32) { c0 = 0.f; c1 = 0.f; c2 = 0.f; }
    wf[mt * 3 + 2] = pk8(c0, c1, c2, 0.f, 0.f, 0.f, 0.f, 0.f);
  }
}

// -------------------------------------------------------------------------
// kV: Vt[l][j][k] register transpose (proven round-7 role 2), 500 blocks.
// -------------------------------------------------------------------------
__global__ __launch_bounds__(256) void kV(const float* __restrict__ Vmu,
                                          const float* __restrict__ Vsg,
                                          const float* __restrict__ Vpi,
                                          _Float16* __restrict__ Vt) {
  const int l = blockIdx.x, tid = threadIdx.x;
  const int w = tid >> 6, lane = tid & 63;
  const int h0 = lane * 8;
  for (int row = w; row < 35; row += 4) {
    const float* src;
    int j, od;
    if (row < O)          { src = Vmu + (size_t)l * H * O; j = row;         od = O; }
    else if (row < 2 * O) { src = Vsg + (size_t)l * H * O; j = row - O;     od = O; }
    else                  { src = Vpi + (size_t)l * H * M; j = row - 2 * O; od = M; }
    float v[8];
#pragma unroll
    for (int e = 0; e < 8; ++e) v[e] = src[(size_t)(h0 + e) * od + j];
    unsigned u[4];
#pragma unroll
    for (int q = 0; q < 4; ++q)
      u[q] = __builtin_bit_cast(unsigned, __builtin_amdgcn_cvt_pkrtz(v[2 * q], v[2 * q + 1]));
    *(uint4*)(Vt + ((size_t)l * JP + row) * KPV + h0) = (uint4){u[0], u[1], u[2], u[3]};
  }
}

// -------------------------------------------------------------------------
// kA: chunk partial sums S_g^T[h][b], direct-read x/W (no staging).
// -------------------------------------------------------------------------
__global__ __launch_bounds__(256, 2) void kA(const float* __restrict__ inp,
                                             const float* __restrict__ z,
                                             const float* __restrict__ W,
                                             _Float16* __restrict__ S) {
  const int idx = blockIdx.x;
  const int g = ((idx >> 6) << 3) + (idx & 7);
  if (g >= G) return;
  const int b0 = ((idx >> 3) & 7) * 32;
  const int w = threadIdx.x >> 6, lane = threadIdx.x & 63;
  const int ln31 = lane & 31, hi32 = lane >> 5;

  f32x16 acc[4];
#pragma unroll
  for (int mt = 0; mt < 4; ++mt)
#pragma unroll
    for (int r = 0; r < 16; ++r) acc[mt][r] = 0.f;

#pragma unroll
  for (int t = 0; t < LC; ++t) {
    const int l = g * LC + t;
    half8 xf[3], wf[12];
    load_x(inp, z, l, b0 + ln31, hi32, xf);
    load_w(W, l, 128 * w, ln31, hi32, wf);
#pragma unroll
    for (int mt = 0; mt < 4; ++mt)
#pragma unroll
      for (int kt = 0; kt < 3; ++kt)
        acc[mt] = __builtin_amdgcn_mfma_f32_32x32x16_f16(wf[mt * 3 + kt], xf[kt], acc[mt], 0, 0, 0);
  }
  // store S^T[g][h][b]: D layout col(b)=ln31, row(h)=(r&3)+8*(r>>2)+4*hi32
  _Float16* Sp = S + ((size_t)g * H + 128 * w) * B + b0 + ln31;
#pragma unroll
  for (int mt = 0; mt < 4; ++mt)
#pragma unroll
    for (int r = 0; r < 16; ++r) {
      const int hl = 32 * mt + (r & 3) + 8 * (r >> 2) + 4 * hi32;
      Sp[(size_t)hl * B] = (_Float16)acc[mt][r];
    }
}

// -------------------------------------------------------------------------
// kS: exclusive scan over the G chunk sums per (h,b), + b_enc. Acc fp16.
// -------------------------------------------------------------------------
__global__ __launch_bounds__(256) void kS(const _Float16* __restrict__ S,
                                          const float* __restrict__ benc,
                                          _Float16* __restrict__ Acc) {
  const int t = blockIdx.x * 256 + threadIdx.x;  // B*H threads
  const int b = t & (B - 1), h = t >> 8;
  float run = benc[h];
  const _Float16* sp = S + (size_t)h * B + b;
  _Float16* ap = Acc + (size_t)h * B + b;
  constexpr size_t stride = (size_t)H * B;
#pragma unroll 5
  for (int g = 0; g < G; ++g) {
    ap[g * stride] = (_Float16)run;  // exclusive: write before adding own chunk
    run += (float)sp[g * stride];
  }
}

// -------------------------------------------------------------------------
// kB: fused scan + projection per chunk. Proven round-5 structure; only the
// recurrence fragment loads switched to direct x/W (coalesced scalar form).
// -------------------------------------------------------------------------
__global__ __launch_bounds__(256, 2) void kB(const float* __restrict__ inp,
                                             const float* __restrict__ z,
                                             const float* __restrict__ W,
                                             const _Float16* __restrict__ Vt,
                                             const _Float16* __restrict__ Acc,
                                             const float* __restrict__ bmu,
                                             const float* __restrict__ bsg,
                                             const float* __restrict__ bpi,
                                             float* __restrict__ out) {
  const int idx = blockIdx.x;
  const int g = ((idx >> 6) << 3) + (idx & 7);
  if (g >= G) return;
  const int b0 = ((idx >> 3) & 7) * 32;
  const int tid = threadIdx.x;
  const int w = tid >> 6, lane = tid & 63;
  const int ln31 = lane & 31, hi32 = lane >> 5;

  __shared__ _Float16 po[4][LC][32][36];  // 46,080 B per-wave partial slabs
  __shared__ float bias_s[LC][35];        // 700 B

  if (tid < LC * 35) {
    const int t = tid / 35, j = tid - 35 * t, l = g * LC + t;
    bias_s[t][j] = (j < O) ? bmu[l * O + j]
                 : (j < 2 * O) ? bsg[l * O + (j - O)]
                 : bpi[l * M + (j - 2 * O)];
  }

  // load running state a = Acc[g] (fp16) into D-layout accumulators
  f32x16 acc[4];
  const _Float16* Ap = Acc + ((size_t)g * H + 128 * w) * B + b0 + ln31;
#pragma unroll
  for (int mt = 0; mt < 4; ++mt)
#pragma unroll
    for (int r = 0; r < 16; ++r) {
      const int hl = 32 * mt + (r & 3) + 8 * (r >> 2) + 4 * hi32;
      acc[mt][r] = (float)Ap[(size_t)hl * B];
    }

#pragma unroll 1
  for (int t = 0; t < LC; ++t) {
    const int l = g * LC + t;
    // ---- issue V loads + (direct) x/W loads for this step up front ----
    const _Float16* Vb = Vt + (size_t)l * JP * KPV + 128 * w + 8 * hi32;
    half8 va0[8];
#pragma unroll
    for (int s = 0; s < 8; ++s)
      va0[s] = *(const half8*)(Vb + 16 * s + (size_t)ln31 * KPV);
    half8 va1[8];
#pragma unroll
    for (int s = 0; s < 8; ++s) {
      va1[s] = half8{};
      if (ln31 < 3)  // j = 32..34 tail rows
        va1[s] = *(const half8*)(Vb + 16 * s + (size_t)(32 + ln31) * KPV);
    }
    half8 xf[3], wf[12];
    if (t != LC - 1) {
      load_x(inp, z, l, b0 + ln31, hi32, xf);
      load_w(W, l, 128 * w, ln31, hi32, wf);
    }
    // ---- projection: out^T[j][b] += V^T[j][h] * relu(a)[h][b] ----
    f32x16 o0, o1;
#pragma unroll
    for (int r = 0; r < 16; ++r) { o0[r] = 0.f; o1[r] = 0.f; }
#pragma unroll
    for (int mt = 0; mt < 4; ++mt) {
      unsigned P0[4], P1[4];
#pragma unroll
      for (int m = 0; m < 4; ++m) {
        float e0 = fmaxf(acc[mt][4 * m + 0], 0.f);
        float e1 = fmaxf(acc[mt][4 * m + 1], 0.f);
        float e2 = fmaxf(acc[mt][4 * m + 2], 0.f);
        float e3 = fmaxf(acc[mt][4 * m + 3], 0.f);
        P0[m] = __builtin_bit_cast(unsigned, __builtin_amdgcn_cvt_pkrtz(e0, e1));
        P1[m] = __builtin_bit_cast(unsigned, __builtin_amdgcn_cvt_pkrtz(e2, e3));
      }
#pragma unroll
      for (int tl = 0; tl < 2; ++tl) {
        // swap vdst.hi <-> vsrc.lo: after swap(X,Y): X=[X.lo|Y.lo], Y=[X.hi|Y.hi]
        unsigned w0 = P0[2 * tl], w2 = P0[2 * tl + 1];
        unsigned w1 = P1[2 * tl], w3 = P1[2 * tl + 1];
        asm("v_permlane32_swap_b32 %0, %1" : "+v"(w0), "+v"(w2));
        asm("v_permlane32_swap_b32 %0, %1" : "+v"(w1), "+v"(w3));
        half2 a0 = __builtin_bit_cast(half2, w0);
        half2 a1 = __builtin_bit_cast(half2, w1);
        half2 a2 = __builtin_bit_cast(half2, w2);
        half2 a3 = __builtin_bit_cast(half2, w3);
        half8 hb = {a0.x, a0.y, a1.x, a1.y, a2.x, a2.y, a3.x, a3.y};
        o0 = __builtin_amdgcn_mfma_f32_32x32x16_f16(va0[2 * mt + tl], hb, o0, 0, 0, 0);
        o1 = __builtin_amdgcn_mfma_f32_32x32x16_f16(va1[2 * mt + tl], hb, o1, 0, 0, 0);
      }
    }
    // ---- per-wave partials to private slab (packed fp16 pairs, no sync) --
    _Float16* pw = &po[w][t][ln31][0];
#pragma unroll
    for (int r = 0; r < 16; r += 2) {
      const int j0 = (r & 3) + 8 * (r >> 2) + 4 * hi32;  // even; pair j0,j0+1
      *(unsigned*)&pw[j0] =
          __builtin_bit_cast(unsigned, __builtin_amdgcn_cvt_pkrtz(o0[r], o0[r + 1]));
    }
    if (hi32 == 0) {  // o1 rows j=32,33,34 live only in hi32==0 lanes
      *(unsigned*)&pw[32] =
          __builtin_bit_cast(unsigned, __builtin_amdgcn_cvt_pkrtz(o1[0], o1[1]));
      pw[34] = (_Float16)o1[2];
    }
    // ---- recurrence: a += (x[l] @ W[l])^T ----
    if (t != LC - 1) {
#pragma unroll
      for (int mt = 0; mt < 4; ++mt)
#pragma unroll
        for (int kt = 0; kt < 3; ++kt)
          acc[mt] = __builtin_amdgcn_mfma_f32_32x32x16_f16(wf[mt * 3 + kt], xf[kt], acc[mt], 0, 0, 0);
    }
  }
  __syncthreads();  // one barrier: po + bias_s visible
  // ---- fused reduce: per b-row 175 contiguous floats (5 l x 35 j) ----
  for (int f = tid; f < 32 * LC * 35; f += 256) {
    const int b = f / (LC * 35);
    const int r = f - b * (LC * 35);
    const int t = r / 35, j = r - 35 * t;
    const float s = (float)po[0][t][b][j] + (float)po[1][t][b][j] +
                    (float)po[2][t][b][j] + (float)po[3][t][b][j];
    out[((size_t)(b0 + b) * L + g * LC + t) * 35 + j] = s + bias_s[t][j];
  }
}

extern "C" void kernel_launch(void* const* d_in, const int* in_sizes, int n_in,
                              void* d_out, int out_size, void* d_ws, size_t ws_size,
                              hipStream_t stream) {
  const float* inp  = (const float*)d_in[0];
  const float* z    = (const float*)d_in[1];
  const float* Wenc = (const float*)d_in[2];
  const float* benc = (const float*)d_in[3];
  const float* Vmu  = (const float*)d_in[4];
  const float* bmu  = (const float*)d_in[5];
  const float* Vsg  = (const float*)d_in[6];
  const float* bsg  = (const float*)d_in[7];
  const float* Vpi  = (const float*)d_in[8];
  const float* bpi  = (const float*)d_in[9];
  float* out = (float*)d_out;

  // Workspace: Vt 24.96 + S 26.21 + Acc 26.21 = 77.4 MB (xT/Wt eliminated)
  char* ws = (char*)d_ws;
  _Float16* Vt  = (_Float16*)ws;                   // [L][48][520]
  _Float16* S   = (_Float16*)(ws + 24960000);      // [G][H][B] fp16
  _Float16* Acc = (_Float16*)(ws + 51174400);      // [G][H][B] fp16

  kV<<<dim3(L), 256, 0, stream>>>(Vmu, Vsg, Vpi, Vt);
  kA<<<dim3(832), 256, 0, stream>>>(inp, z, Wenc, S);
  kS<<<dim3(B * H / 256), 256, 0, stream>>>(S, benc, Acc);
  kB<<<dim3(832), 256, 0, stream>>>(inp, z, Wenc, Vt, Acc, bmu, bsg, bpi, out);
}

// Round 11
// 238.113 us; speedup vs baseline: 1.1325x; 1.1325x over previous
//
#include <hip/hip_runtime.h>

// Problem constants (from reference)
constexpr int B = 256, L = 500, D = 3, C = 32, I = 35, H = 512, O = 15, M = 5;
constexpr int KP1 = 48;  // GEMM1 K-dim (I=35) zero-padded to 3 MFMA k-steps (32x32x16)
constexpr int JP = 48;   // Vt row stride (rows 0..34 live)
constexpr int KPV = 520; // padded K leading dim for Vt
constexpr int G = 125;   // scan chunks (round-11: was 100; more kB co-residency)
constexpr int LC = 4;    // L / G

typedef __attribute__((ext_vector_type(8))) _Float16 half8;  // MFMA A/B frag
typedef __attribute__((ext_vector_type(2))) _Float16 half2;
typedef __attribute__((ext_vector_type(16))) float f32x16;   // 32x32 C/D frag

// -------------------------------------------------------------------------
// kP01: xT + Wt preps (proven round-8 roles 0/1), zero LDS, grid 3L.
// -------------------------------------------------------------------------
__global__ __launch_bounds__(256, 2) void kP01(const float* __restrict__ inp,
                                               const float* __restrict__ z,
                                               const float* __restrict__ W,
                                               _Float16* __restrict__ xT,
                                               _Float16* __restrict__ Wt) {
  const int bx = blockIdx.x, tid = threadIdx.x;

  if (bx < L) {
    // ---- role 0: xT[l][b][k], K padded to 48 ----
    const int l = bx, b = tid;
    float e[36];
    const float* ip = inp + ((size_t)b * L + l) * D;
    e[0] = ip[0]; e[1] = ip[1]; e[2] = ip[2];
    const float4* zp = (const float4*)(z + ((size_t)b * L + l) * C);
#pragma unroll
    for (int q = 0; q < 8; ++q) {
      float4 v = zp[q];
      e[D + 4 * q + 0] = v.x; e[D + 4 * q + 1] = v.y;
      e[D + 4 * q + 2] = v.z; e[D + 4 * q + 3] = v.w;
    }
    e[35] = 0.f;
    unsigned u[24];
#pragma unroll
    for (int q = 0; q < 18; ++q)
      u[q] = __builtin_bit_cast(unsigned, __builtin_amdgcn_cvt_pkrtz(e[2 * q], e[2 * q + 1]));
#pragma unroll
    for (int q = 18; q < 24; ++q) u[q] = 0u;
    uint4* dst = (uint4*)(xT + ((size_t)l * B + b) * KP1);
#pragma unroll
    for (int q = 0; q < 6; ++q) dst[q] = ((const uint4*)u)[q];
  } else {
    // ---- role 1: Wt[l][h][k], one 256-h pass per block ----
    const int t = bx - L;
    const int l = t >> 1, hp = t & 1;
    const int h = tid + 256 * hp;
    float v[36];
#pragma unroll
    for (int i = 0; i < I; ++i) v[i] = W[((size_t)l * I + i) * H + h];  // coalesced
    v[35] = 0.f;
    unsigned u[24];
#pragma unroll
    for (int q = 0; q < 18; ++q)
      u[q] = __builtin_bit_cast(unsigned, __builtin_amdgcn_cvt_pkrtz(v[2 * q], v[2 * q + 1]));
#pragma unroll
    for (int q = 18; q < 24; ++q) u[q] = 0u;
    uint4* dst = (uint4*)(Wt + ((size_t)l * H + h) * KP1);
#pragma unroll
    for (int q = 0; q < 6; ++q) dst[q] = ((const uint4*)u)[q];
  }
}

// -------------------------------------------------------------------------
// kP2: Vt[l][j][k] via LDS transpose. Round-7/8 read V at stride 60B = ~60
// cache lines per wave-instruction (~8.6M line transactions — the dominant
// scatter in kPrep). Here: COALESCED global reads (linear idx) -> LDS
// scatter (cheap) -> coalesced uint4 writes. No zero-fill (35 rows only,
// cols 512..519 pad garbage never read). 36.4 KB LDS, own kernel so the
// xT/Wt roles don't pay the LDS occupancy tax.
// -------------------------------------------------------------------------
__global__ __launch_bounds__(256) void kP2(const float* __restrict__ Vmu,
                                           const float* __restrict__ Vsg,
                                           const float* __restrict__ Vpi,
                                           _Float16* __restrict__ Vt) {
  const int l = blockIdx.x, tid = threadIdx.x;
  __shared__ __align__(16) _Float16 Vs[35][KPV];  // 36,400 B
  const float* vm = Vmu + (size_t)l * H * O;
  const float* vs = Vsg + (size_t)l * H * O;
  const float* vp = Vpi + (size_t)l * H * M;
  for (int idx = tid; idx < H * O; idx += 256) {
    int k = idx / O, j = idx - k * O;
    Vs[j][k]     = (_Float16)vm[idx];
    Vs[O + j][k] = (_Float16)vs[idx];
  }
  for (int idx = tid; idx < H * M; idx += 256) {
    int k = idx / M, j = idx - k * M;
    Vs[2 * O + j][k] = (_Float16)vp[idx];
  }
  __syncthreads();
  uint4* dst = (uint4*)(Vt + (size_t)l * JP * KPV);
  // 35 rows x 65 uint4 per row; Vt row stride = 520 halves = 65 uint4 exactly
  for (int f = tid; f < 35 * 65; f += 256) {
    int row = f / 65, q = f - row * 65;
    dst[(size_t)row * 65 + q] = *(const uint4*)&Vs[row][q * 8];
  }
}

// -------------------------------------------------------------------------
// kA: chunk partial sums S_g^T[h][b] (staged xT/Wt — round-10 proved direct
// reads regress). Full t-unroll. Grid 1024 (125 chunks x 8 b-blocks).
// -------------------------------------------------------------------------
__global__ __launch_bounds__(256, 3) void kA(const _Float16* __restrict__ xT,
                                             const _Float16* __restrict__ Wt,
                                             _Float16* __restrict__ S) {
  const int idx = blockIdx.x;
  const int g = ((idx >> 6) << 3) + (idx & 7);
  if (g >= G) return;
  const int b0 = ((idx >> 3) & 7) * 32;
  const int w = threadIdx.x >> 6, lane = threadIdx.x & 63;
  const int ln31 = lane & 31, hi32 = lane >> 5;

  f32x16 acc[4];
#pragma unroll
  for (int mt = 0; mt < 4; ++mt)
#pragma unroll
    for (int r = 0; r < 16; ++r) acc[mt][r] = 0.f;

#pragma unroll
  for (int t = 0; t < LC; ++t) {
    const int l = g * LC + t;
    const _Float16* Xb = xT + ((size_t)l * B + b0 + ln31) * KP1 + 8 * hi32;
    const _Float16* Wb = Wt + ((size_t)l * H + 128 * w + ln31) * KP1 + 8 * hi32;
    half8 xf[3], wf[12];
#pragma unroll
    for (int kt = 0; kt < 3; ++kt) xf[kt] = *(const half8*)(Xb + 16 * kt);
#pragma unroll
    for (int mt = 0; mt < 4; ++mt)
#pragma unroll
      for (int kt = 0; kt < 3; ++kt)
        wf[mt * 3 + kt] = *(const half8*)(Wb + (size_t)mt * 32 * KP1 + 16 * kt);
#pragma unroll
    for (int mt = 0; mt < 4; ++mt)
#pragma unroll
      for (int kt = 0; kt < 3; ++kt)
        acc[mt] = __builtin_amdgcn_mfma_f32_32x32x16_f16(wf[mt * 3 + kt], xf[kt], acc[mt], 0, 0, 0);
  }
  // store S^T[g][h][b]: D layout col(b)=ln31, row(h)=(r&3)+8*(r>>2)+4*hi32
  _Float16* Sp = S + ((size_t)g * H + 128 * w) * B + b0 + ln31;
#pragma unroll
  for (int mt = 0; mt < 4; ++mt)
#pragma unroll
    for (int r = 0; r < 16; ++r) {
      const int hl = 32 * mt + (r & 3) + 8 * (r >> 2) + 4 * hi32;
      Sp[(size_t)hl * B] = (_Float16)acc[mt][r];
    }
}

// -------------------------------------------------------------------------
// kS: exclusive scan over the G chunk sums per (h,b), + b_enc. Acc fp16.
// -------------------------------------------------------------------------
__global__ __launch_bounds__(256) void kS(const _Float16* __restrict__ S,
                                          const float* __restrict__ benc,
                                          _Float16* __restrict__ Acc) {
  const int t = blockIdx.x * 256 + threadIdx.x;  // B*H threads
  const int b = t & (B - 1), h = t >> 8;
  float run = benc[h];
  const _Float16* sp = S + (size_t)h * B + b;
  _Float16* ap = Acc + (size_t)h * B + b;
  constexpr size_t stride = (size_t)H * B;
#pragma unroll 5
  for (int g = 0; g < G; ++g) {
    ap[g * stride] = (_Float16)run;  // exclusive: write before adding own chunk
    run += (float)sp[g * stride];
  }
}

// -------------------------------------------------------------------------
// kB: fused scan + projection per chunk (proven round-5/8 structure,
// staged operands). LC=4: po 36,864B -> LDS allows 4 blocks/CU; grid 1024.
// -------------------------------------------------------------------------
__global__ __launch_bounds__(256, 2) void kB(const _Float16* __restrict__ xT,
                                             const _Float16* __restrict__ Wt,
                                             const _Float16* __restrict__ Vt,
                                             const _Float16* __restrict__ Acc,
                                             const float* __restrict__ bmu,
                                             const float* __restrict__ bsg,
                                             const float* __restrict__ bpi,
                                             float* __restrict__ out) {
  const int idx = blockIdx.x;
  const int g = ((idx >> 6) << 3) + (idx & 7);
  if (g >= G) return;
  const int b0 = ((idx >> 3) & 7) * 32;
  const int tid = threadIdx.x;
  const int w = tid >> 6, lane = tid & 63;
  const int ln31 = lane & 31, hi32 = lane >> 5;

  __shared__ _Float16 po[4][LC][32][36];  // 36,864 B per-wave partial slabs
  __shared__ float bias_s[LC][35];        // 560 B

  // stage bias once per block
  if (tid < LC * 35) {
    const int t = tid / 35, j = tid - 35 * t, l = g * LC + t;
    bias_s[t][j] = (j < O) ? bmu[l * O + j]
                 : (j < 2 * O) ? bsg[l * O + (j - O)]
                 : bpi[l * M + (j - 2 * O)];
  }

  // load running state a = Acc[g] (fp16) into D-layout accumulators
  f32x16 acc[4];
  const _Float16* Ap = Acc + ((size_t)g * H + 128 * w) * B + b0 + ln31;
#pragma unroll
  for (int mt = 0; mt < 4; ++mt)
#pragma unroll
    for (int r = 0; r < 16; ++r) {
      const int hl = 32 * mt + (r & 3) + 8 * (r >> 2) + 4 * hi32;
      acc[mt][r] = (float)Ap[(size_t)hl * B];
    }

#pragma unroll 1
  for (int t = 0; t < LC; ++t) {
    const int l = g * LC + t;
    // ---- issue ALL loads for this step up front ----
    const _Float16* Vb = Vt + (size_t)l * JP * KPV + 128 * w + 8 * hi32;
    half8 va0[8];
#pragma unroll
    for (int s = 0; s < 8; ++s)
      va0[s] = *(const half8*)(Vb + 16 * s + (size_t)ln31 * KPV);
    half8 va1[8];
#pragma unroll
    for (int s = 0; s < 8; ++s) {
      va1[s] = half8{};
      if (ln31 < 3)  // j = 32..34 tail rows
        va1[s] = *(const half8*)(Vb + 16 * s + (size_t)(32 + ln31) * KPV);
    }
    half8 xf[3], wf[12];
    if (t != LC - 1) {
      const _Float16* Xb = xT + ((size_t)l * B + b0 + ln31) * KP1 + 8 * hi32;
      const _Float16* Wb = Wt + ((size_t)l * H + 128 * w + ln31) * KP1 + 8 * hi32;
#pragma unroll
      for (int kt = 0; kt < 3; ++kt) xf[kt] = *(const half8*)(Xb + 16 * kt);
#pragma unroll
      for (int mt = 0; mt < 4; ++mt)
#pragma unroll
        for (int kt = 0; kt < 3; ++kt)
          wf[mt * 3 + kt] = *(const half8*)(Wb + (size_t)mt * 32 * KP1 + 16 * kt);
    }
    // ---- projection: out^T[j][b] += V^T[j][h] * relu(a)[h][b] ----
    f32x16 o0, o1;
#pragma unroll
    for (int r = 0; r < 16; ++r) { o0[r] = 0.f; o1[r] = 0.f; }
#pragma unroll
    for (int mt = 0; mt < 4; ++mt) {
      unsigned P0[4], P1[4];
#pragma unroll
      for (int m = 0; m < 4; ++m) {
        float e0 = fmaxf(acc[mt][4 * m + 0], 0.f);
        float e1 = fmaxf(acc[mt][4 * m + 1], 0.f);
        float e2 = fmaxf(acc[mt][4 * m + 2], 0.f);
        float e3 = fmaxf(acc[mt][4 * m + 3], 0.f);
        P0[m] = __builtin_bit_cast(unsigned, __builtin_amdgcn_cvt_pkrtz(e0, e1));
        P1[m] = __builtin_bit_cast(unsigned, __builtin_amdgcn_cvt_pkrtz(e2, e3));
      }
#pragma unroll
      for (int tl = 0; tl < 2; ++tl) {
        // swap vdst.hi <-> vsrc.lo: after swap(X,Y): X=[X.lo|Y.lo], Y=[X.hi|Y.hi]
        unsigned w0 = P0[2 * tl], w2 = P0[2 * tl + 1];
        unsigned w1 = P1[2 * tl], w3 = P1[2 * tl + 1];
        asm("v_permlane32_swap_b32 %0, %1" : "+v"(w0), "+v"(w2));
        asm("v_permlane32_swap_b32 %0, %1" : "+v"(w1), "+v"(w3));
        half2 a0 = __builtin_bit_cast(half2, w0);
        half2 a1 = __builtin_bit_cast(half2, w1);
        half2 a2 = __builtin_bit_cast(half2, w2);
        half2 a3 = __builtin_bit_cast(half2, w3);
        half8 hb = {a0.x, a0.y, a1.x, a1.y, a2.x, a2.y, a3.x, a3.y};
        o0 = __builtin_amdgcn_mfma_f32_32x32x16_f16(va0[2 * mt + tl], hb, o0, 0, 0, 0);
        o1 = __builtin_amdgcn_mfma_f32_32x32x16_f16(va1[2 * mt + tl], hb, o1, 0, 0, 0);
      }
    }
    // ---- per-wave partials to private slab (packed fp16 pairs, no sync) --
    _Float16* pw = &po[w][t][ln31][0];
#pragma unroll
    for (int r = 0; r < 16; r += 2) {
      const int j0 = (r & 3) + 8 * (r >> 2) + 4 * hi32;  // even; pair j0,j0+1
      *(unsigned*)&pw[j0] =
          __builtin_bit_cast(unsigned, __builtin_amdgcn_cvt_pkrtz(o0[r], o0[r + 1]));
    }
    if (hi32 == 0) {  // o1 rows j=32,33,34 live only in hi32==0 lanes
      *(unsigned*)&pw[32] =
          __builtin_bit_cast(unsigned, __builtin_amdgcn_cvt_pkrtz(o1[0], o1[1]));
      pw[34] = (_Float16)o1[2];
    }
    // ---- recurrence: a += (x[l] @ W[l])^T ----
    if (t != LC - 1) {
#pragma unroll
      for (int mt = 0; mt < 4; ++mt)
#pragma unroll
        for (int kt = 0; kt < 3; ++kt)
          acc[mt] = __builtin_amdgcn_mfma_f32_32x32x16_f16(wf[mt * 3 + kt], xf[kt], acc[mt], 0, 0, 0);
    }
  }
  __syncthreads();  // one barrier: po + bias_s visible
  // ---- fused reduce: per b-row LC*35 contiguous floats ----
  for (int f = tid; f < 32 * LC * 35; f += 256) {
    const int b = f / (LC * 35);
    const int r = f - b * (LC * 35);
    const int t = r / 35, j = r - 35 * t;
    const float s = (float)po[0][t][b][j] + (float)po[1][t][b][j] +
                    (float)po[2][t][b][j] + (float)po[3][t][b][j];
    out[((size_t)(b0 + b) * L + g * LC + t) * 35 + j] = s + bias_s[t][j];
  }
}

extern "C" void kernel_launch(void* const* d_in, const int* in_sizes, int n_in,
                              void* d_out, int out_size, void* d_ws, size_t ws_size,
                              hipStream_t stream) {
  const float* inp  = (const float*)d_in[0];
  const float* z    = (const float*)d_in[1];
  const float* Wenc = (const float*)d_in[2];
  const float* benc = (const float*)d_in[3];
  const float* Vmu  = (const float*)d_in[4];
  const float* bmu  = (const float*)d_in[5];
  const float* Vsg  = (const float*)d_in[6];
  const float* bsg  = (const float*)d_in[7];
  const float* Vpi  = (const float*)d_in[8];
  const float* bpi  = (const float*)d_in[9];
  float* out = (float*)d_out;

  // Workspace: xT 12.29 + Wt 24.58 + Vt 24.96 + S 32.77 + Acc 32.77 = 127.4 MB
  char* ws = (char*)d_ws;
  _Float16* xT  = (_Float16*)ws;                   // [L][B][48]
  _Float16* Wt  = (_Float16*)(ws + 12288000);      // [L][H][48]
  _Float16* Vt  = (_Float16*)(ws + 36864000);      // [L][48][520]
  _Float16* S   = (_Float16*)(ws + 61824000);      // [G][H][B] fp16
  _Float16* Acc = (_Float16*)(ws + 94592000);      // [G][H][B] fp16

  kP01<<<dim3(3 * L), 256, 0, stream>>>(inp, z, Wenc, xT, Wt);
  kP2<<<dim3(L), 256, 0, stream>>>(Vmu, Vsg, Vpi, Vt);
  kA<<<dim3(1024), 256, 0, stream>>>(xT, Wt, S);
  kS<<<dim3(B * H / 256), 256, 0, stream>>>(S, benc, Acc);
  kB<<<dim3(1024), 256, 0, stream>>>(xT, Wt, Vt, Acc, bmu, bsg, bpi, out);
}